// Round 18
// baseline (1637.947 us; speedup 1.0000x reference)
//
#include <hip/hip_runtime.h>

#define BB 128
#define TT 2048
#define HH 64

typedef float2 f2;
struct f2x2 { f2 lo, hi; };

__device__ __forceinline__ float sigm(float v) {
    return __builtin_amdgcn_rcpf(1.0f + __expf(-v));
}
__device__ __forceinline__ float ftanh(float v) {
    float e = __expf(-2.0f * fabsf(v));
    float r = (1.0f - e) * __builtin_amdgcn_rcpf(1.0f + e);
    return copysignf(r, v);
}

#define PIN2(v) asm volatile("" : "+v"(v))
// packed fp32 FMA: 1 inst / 2 MACs (VOP3P)
#define PKFMA(acc, w, h) \
    asm("v_pk_fma_f32 %0, %1, %2, %0" : "+v"(acc) : "v"(w), "v"(h))
// split a float4 (4 consecutive VGPRs) into two f2 register pairs, no movs
#define SPLIT(v4, lo_, hi_) \
    { f2x2 u_ = __builtin_bit_cast(f2x2, (v4)); lo_ = u_.lo; hi_ = u_.hi; }

// + lane^1 via quad_perm DPP (VALU pipe, not LDS)
__device__ __forceinline__ float dppadd1(float v) {
    int s_ = __builtin_bit_cast(int, v);
    int p_ = __builtin_amdgcn_update_dpp(0, s_, 0xB1, 0xF, 0xF, true);
    return v + __builtin_bit_cast(float, p_);
}

// R18 = R15 (6 waves, 96 weight-floats/lane, hard barrier — R17's soft
// barrier regressed 18%, reverted) x TWO BATCHES PER BLOCK.
// The same weight registers serve 2 independent recurrent chains: per step a
// wave does 2x dots/gates, but the barrier convoy, LDS-burst drain, and
// dependency-chain latency are paid ONCE per 2 batch-steps. 64 blocks spread
// 1/CU over 256 CUs. LDS ~103KB (>80KB keeps the 1-block/CU static target ->
// VGPR cap 256 at 2 waves/SIMD; need ~180).
// Wave->stage map (wave i -> SIMD i%4):
//   w0(s0,h0) w1(s2,h0) w2(s0,h1) w3(s2,h1) w4(s1,h0,+flush b0) w5(s1,h1,+flush b1)
//   s=0: h1(i)  = GRU1(h1(i-1), x(i))          [h1b parity]
//   s=1: xg(i-1)= Wih1*h1(i-1)+bih1            [xgb4 parity, packed float4]
//   s=2: h2(i-2)= GRU2(h2(i-3), xg(i-2))       [h2b parity, ring store]
// fc head: w4/w5 flush 64 outputs (batch 0/1) every 64 iters from the ring.
__global__ __launch_bounds__(384)
__attribute__((amdgpu_waves_per_eu(1, 2)))
void gru_fused(const float* __restrict__ x,
               const float* __restrict__ Wih0, const float* __restrict__ Whh0,
               const float* __restrict__ bih0, const float* __restrict__ bhh0,
               const float* __restrict__ Wih1, const float* __restrict__ Whh1,
               const float* __restrict__ bih1, const float* __restrict__ bhh1,
               const float* __restrict__ fcw, const float* __restrict__ fcb,
               float* __restrict__ out)
{
    const int t  = threadIdx.x;
    const int w  = t >> 6;          // wave 0..5
    const int j  = t & 63;          // lane
    const int s  = (w < 4) ? ((w & 1) ? 2 : 0) : 1;   // stage
    const int sw = (w < 4) ? (w >> 1) : (w & 1);      // dim half
    const int g  = j >> 1;          // local dim 0..31
    const int q  = j & 1;           // K-half
    const int d  = sw * 32 + g;     // dim 0..63
    const int blk = blockIdx.x;     // 2 batches: 2*blk, 2*blk+1

    __shared__ __align__(16) float xs[2 * TT * 2];   // 32 KB input (2 batches)
    __shared__ __align__(16) float h1b[2][2][HH];    // [parity][batch][dim]
    __shared__ __align__(16) float h2b[2][2][HH];
    __shared__ __align__(16) float4 xgb4[2][2][HH];  // [parity][batch][dim]
    __shared__ __align__(16) float fwS[HH];
    __shared__ float ring[2][128][65];               // [batch] h2 history
    // total ~103 KB: >80KB on purpose (1-block/CU static VGPR target)

    // ---- 96 weight floats as 48 named f2 (3 rows x 32 cols) ----
    const float* Wm = (s == 0) ? Whh0 : (s == 1) ? Wih1 : Whh1;
    const float4* P0 = (const float4*)(Wm + (size_t)(0 * HH + d) * HH + q * 32);
    const float4* P1 = (const float4*)(Wm + (size_t)(1 * HH + d) * HH + q * 32);
    const float4* P2 = (const float4*)(Wm + (size_t)(2 * HH + d) * HH + q * 32);
    f2 wa0, wa1, wa2, wa3, wa4, wa5, wa6, wa7,
       wa8, wa9, wa10, wa11, wa12, wa13, wa14, wa15;
    f2 wb0, wb1, wb2, wb3, wb4, wb5, wb6, wb7,
       wb8, wb9, wb10, wb11, wb12, wb13, wb14, wb15;
    f2 wc0, wc1, wc2, wc3, wc4, wc5, wc6, wc7,
       wc8, wc9, wc10, wc11, wc12, wc13, wc14, wc15;
    {
        float4 v;
        v = P0[0]; SPLIT(v, wa0,  wa1);  v = P0[1]; SPLIT(v, wa2,  wa3);
        v = P0[2]; SPLIT(v, wa4,  wa5);  v = P0[3]; SPLIT(v, wa6,  wa7);
        v = P0[4]; SPLIT(v, wa8,  wa9);  v = P0[5]; SPLIT(v, wa10, wa11);
        v = P0[6]; SPLIT(v, wa12, wa13); v = P0[7]; SPLIT(v, wa14, wa15);
        v = P1[0]; SPLIT(v, wb0,  wb1);  v = P1[1]; SPLIT(v, wb2,  wb3);
        v = P1[2]; SPLIT(v, wb4,  wb5);  v = P1[3]; SPLIT(v, wb6,  wb7);
        v = P1[4]; SPLIT(v, wb8,  wb9);  v = P1[5]; SPLIT(v, wb10, wb11);
        v = P1[6]; SPLIT(v, wb12, wb13); v = P1[7]; SPLIT(v, wb14, wb15);
        v = P2[0]; SPLIT(v, wc0,  wc1);  v = P2[1]; SPLIT(v, wc2,  wc3);
        v = P2[2]; SPLIT(v, wc4,  wc5);  v = P2[3]; SPLIT(v, wc6,  wc7);
        v = P2[4]; SPLIT(v, wc8,  wc9);  v = P2[5]; SPLIT(v, wc10, wc11);
        v = P2[6]; SPLIT(v, wc12, wc13); v = P2[7]; SPLIT(v, wc14, wc15);
    }
    PIN2(wa0);  PIN2(wa1);  PIN2(wa2);  PIN2(wa3);
    PIN2(wa4);  PIN2(wa5);  PIN2(wa6);  PIN2(wa7);
    PIN2(wa8);  PIN2(wa9);  PIN2(wa10); PIN2(wa11);
    PIN2(wa12); PIN2(wa13); PIN2(wa14); PIN2(wa15);
    PIN2(wb0);  PIN2(wb1);  PIN2(wb2);  PIN2(wb3);
    PIN2(wb4);  PIN2(wb5);  PIN2(wb6);  PIN2(wb7);
    PIN2(wb8);  PIN2(wb9);  PIN2(wb10); PIN2(wb11);
    PIN2(wb12); PIN2(wb13); PIN2(wb14); PIN2(wb15);
    PIN2(wc0);  PIN2(wc1);  PIN2(wc2);  PIN2(wc3);
    PIN2(wc4);  PIN2(wc5);  PIN2(wc6);  PIN2(wc7);
    PIN2(wc8);  PIN2(wc9);  PIN2(wc10); PIN2(wc11);
    PIN2(wc12); PIN2(wc13); PIN2(wc14); PIN2(wc15);

    // biases (added AFTER the reduce, so loaded once per lane)
    float kb0, kb1, kb2, bi2 = 0.f;
    if (s == 0) {            // r,z: fold bih0+bhh0; n: bhh0 inside r*(), bih0 outside
        kb0 = bhh0[d] + bih0[d];
        kb1 = bhh0[HH + d] + bih0[HH + d];
        kb2 = bhh0[2 * HH + d];
        bi2 = bih0[2 * HH + d];
    } else if (s == 1) {
        kb0 = bih1[d]; kb1 = bih1[HH + d]; kb2 = bih1[2 * HH + d];
    } else {
        kb0 = bhh1[d]; kb1 = bhh1[HH + d]; kb2 = bhh1[2 * HH + d];
    }
    float wi0 = 0, wi1 = 0, wi2 = 0, wi3 = 0, wi4 = 0, wi5 = 0;
    if (s == 0) {
        wi0 = Wih0[d * 2];            wi1 = Wih0[d * 2 + 1];
        wi2 = Wih0[(HH + d) * 2];     wi3 = Wih0[(HH + d) * 2 + 1];
        wi4 = Wih0[(2 * HH + d) * 2]; wi5 = Wih0[(2 * HH + d) * 2 + 1];
    }
    const float fcbv = fcb[0];

    // ---- preload x (both batches, contiguous in global), zero state ----
    {
        const float4* xp  = (const float4*)(x + (size_t)(2 * blk) * TT * 2);
        float4*       xsp = (float4*)xs;
        for (int i2 = t; i2 < 2 * TT * 2 / 4; i2 += 384) xsp[i2] = xp[i2];
    }
    if (t < 4 * HH) { ((float*)h1b)[t] = 0.f; ((float*)h2b)[t] = 0.f; }
    if (t < HH) fwS[t] = fcw[t];

    float hreg0 = 0.f, hreg1 = 0.f;  // s0: h1[d] per batch; s2: h2[d] per batch

// One batch's work within a step (bb_ literal, hr_ = its h register)
#define BATCH(bb_, hr_, i_, PC, PP)                                            \
    {                                                                          \
        const float4* hp = ((const float4*)((s < 2) ? h1b[PP][bb_]             \
                                                    : h2b[PP][bb_])) + q * 8;  \
        f2 h0, h1, h2, h3, h4, h5, h6, h7,                                     \
           h8, h9, h10, h11, h12, h13, h14, h15;                               \
        {                                                                      \
            float4 v_;                                                         \
            v_ = hp[0]; SPLIT(v_, h0,  h1);  v_ = hp[1]; SPLIT(v_, h2,  h3);   \
            v_ = hp[2]; SPLIT(v_, h4,  h5);  v_ = hp[3]; SPLIT(v_, h6,  h7);   \
            v_ = hp[4]; SPLIT(v_, h8,  h9);  v_ = hp[5]; SPLIT(v_, h10, h11);  \
            v_ = hp[6]; SPLIT(v_, h12, h13); v_ = hp[7]; SPLIT(v_, h14, h15);  \
        }                                                                      \
        f2 aR = {0.f, 0.f}, aZ = {0.f, 0.f}, aN = {0.f, 0.f};                  \
        PKFMA(aR, wa0,  h0);  PKFMA(aZ, wb0,  h0);  PKFMA(aN, wc0,  h0);       \
        PKFMA(aR, wa1,  h1);  PKFMA(aZ, wb1,  h1);  PKFMA(aN, wc1,  h1);       \
        PKFMA(aR, wa2,  h2);  PKFMA(aZ, wb2,  h2);  PKFMA(aN, wc2,  h2);       \
        PKFMA(aR, wa3,  h3);  PKFMA(aZ, wb3,  h3);  PKFMA(aN, wc3,  h3);       \
        PKFMA(aR, wa4,  h4);  PKFMA(aZ, wb4,  h4);  PKFMA(aN, wc4,  h4);       \
        PKFMA(aR, wa5,  h5);  PKFMA(aZ, wb5,  h5);  PKFMA(aN, wc5,  h5);       \
        PKFMA(aR, wa6,  h6);  PKFMA(aZ, wb6,  h6);  PKFMA(aN, wc6,  h6);       \
        PKFMA(aR, wa7,  h7);  PKFMA(aZ, wb7,  h7);  PKFMA(aN, wc7,  h7);       \
        PKFMA(aR, wa8,  h8);  PKFMA(aZ, wb8,  h8);  PKFMA(aN, wc8,  h8);       \
        PKFMA(aR, wa9,  h9);  PKFMA(aZ, wb9,  h9);  PKFMA(aN, wc9,  h9);       \
        PKFMA(aR, wa10, h10); PKFMA(aZ, wb10, h10); PKFMA(aN, wc10, h10);      \
        PKFMA(aR, wa11, h11); PKFMA(aZ, wb11, h11); PKFMA(aN, wc11, h11);      \
        PKFMA(aR, wa12, h12); PKFMA(aZ, wb12, h12); PKFMA(aN, wc12, h12);      \
        PKFMA(aR, wa13, h13); PKFMA(aZ, wb13, h13); PKFMA(aN, wc13, h13);      \
        PKFMA(aR, wa14, h14); PKFMA(aZ, wb14, h14); PKFMA(aN, wc14, h14);      \
        PKFMA(aR, wa15, h15); PKFMA(aZ, wb15, h15); PKFMA(aN, wc15, h15);      \
        float sr = aR.x + aR.y, sz = aZ.x + aZ.y, sn = aN.x + aN.y;            \
        sr = dppadd1(sr); sz = dppadd1(sz); sn = dppadd1(sn);                  \
        sr += kb0; sz += kb1; sn += kb2;                                       \
        if (s == 0) {                                                          \
            f2 xv = *(const f2*)(xs + bb_ * TT * 2 + 2 * i_);                  \
            float rr = sigm (fmaf(wi0, xv.x, fmaf(wi1, xv.y, sr)));            \
            float zz = sigm (fmaf(wi2, xv.x, fmaf(wi3, xv.y, sz)));            \
            float nn = ftanh(fmaf(wi4, xv.x, fmaf(wi5, xv.y, bi2)) + rr * sn); \
            hr_ = (1.f - zz) * nn + zz * hr_;                                  \
            if (q == 0) h1b[PC][bb_][d] = hr_;                                 \
        } else if (s == 1) {                                                   \
            if (q == 0) xgb4[PP][bb_][d] = make_float4(sr, sz, sn, 0.f);       \
        } else {                                                               \
            float4 xg = xgb4[PC][bb_][d];                                      \
            float rr = sigm (xg.x + sr);                                       \
            float zz = sigm (xg.y + sz);                                       \
            float nn = ftanh(xg.z + rr * sn);                                  \
            hr_ = (1.f - zz) * nn + zz * hr_;                                  \
            if (q == 0) {                                                      \
                h2b[PC][bb_][d] = hr_;                                         \
                ring[bb_][(i_ - 2) & 127][d] = hr_;                            \
            }                                                                  \
        }                                                                      \
    }

// One timestep for BOTH batches. PC/PP literals; FL only in even steps.
#define STEP(IDX, PC, PP, FL)                                                  \
    {                                                                          \
        __syncthreads();                                                       \
        const int i_ = (IDX);                                                  \
        const bool act = (s == 0) ? (i_ < TT)                                  \
                       : (s == 1) ? (i_ >= 1 && i_ <= TT)                      \
                                  : (i_ >= 2);                                 \
        if (act) {                                                             \
            BATCH(0, hreg0, i_, PC, PP);                                       \
            BATCH(1, hreg1, i_, PC, PP);                                       \
        }                                                                      \
        if (FL && w >= 4 && i_ >= 66 && ((i_ - 66) & 63) == 0) {               \
            const int fb = w - 4;                                              \
            const int tt = ((i_ - 66) >> 6) * 64 + j;                          \
            const float* rr2 = ring[fb][tt & 127];                             \
            float acc0 = 0.f, acc1 = 0.f;                                      \
            _Pragma("unroll")                                                  \
            for (int k = 0; k < 64; k += 2) {                                  \
                acc0 += rr2[k]     * fwS[k];                                   \
                acc1 += rr2[k + 1] * fwS[k + 1];                               \
            }                                                                  \
            out[(size_t)(2 * blk + fb) * TT + tt] = acc0 + acc1 + fcbv;        \
        }                                                                      \
    }

    __syncthreads();    // preload visible
    for (int ii = 0; ii < TT + 2; ii += 2) {
        STEP(ii,     0, 1, true);     // even step: parity (0,1), flush check
        STEP(ii + 1, 1, 0, false);    // odd  step: parity (1,0)
    }
#undef STEP
#undef BATCH

    __syncthreads();
    if (w >= 4) {                                // final chunk: t = 1984..2047
        const int fb = w - 4;
        const int tt = 31 * 64 + j;
        const float* rr2 = ring[fb][tt & 127];
        float acc0 = 0.f, acc1 = 0.f;
        #pragma unroll
        for (int k = 0; k < 64; k += 2) {
            acc0 += rr2[k]     * fwS[k];
            acc1 += rr2[k + 1] * fwS[k + 1];
        }
        out[(size_t)(2 * blk + fb) * TT + tt] = acc0 + acc1 + fcbv;
    }
}

extern "C" void kernel_launch(void* const* d_in, const int* in_sizes, int n_in,
                              void* d_out, int out_size, void* d_ws, size_t ws_size,
                              hipStream_t stream) {
    const float* x    = (const float*)d_in[0];
    const float* Wih0 = (const float*)d_in[1];
    const float* Whh0 = (const float*)d_in[2];
    const float* bih0 = (const float*)d_in[3];
    const float* bhh0 = (const float*)d_in[4];
    const float* Wih1 = (const float*)d_in[5];
    const float* Whh1 = (const float*)d_in[6];
    const float* bih1 = (const float*)d_in[7];
    const float* bhh1 = (const float*)d_in[8];
    const float* fcw  = (const float*)d_in[9];
    const float* fcb  = (const float*)d_in[10];
    float* out = (float*)d_out;

    gru_fused<<<BB / 2, 384, 0, stream>>>(x, Wih0, Whh0, bih0, bhh0,
                                          Wih1, Whh1, bih1, bhh1, fcw, fcb, out);
}

// Round 19
// 1146.474 us; speedup vs baseline: 1.4287x; 1.4287x over previous
//
#include <hip/hip_runtime.h>

#define BB 128
#define TT 2048
#define HH 64

typedef float2 f2;
struct f2x2 { f2 lo, hi; };

__device__ __forceinline__ float sigm(float v) {
    return __builtin_amdgcn_rcpf(1.0f + __expf(-v));
}
__device__ __forceinline__ float ftanh(float v) {
    float e = __expf(-2.0f * fabsf(v));
    float r = (1.0f - e) * __builtin_amdgcn_rcpf(1.0f + e);
    return copysignf(r, v);
}

#define PIN2(v) asm volatile("" : "+v"(v))
// packed fp32 FMA: 1 inst / 2 MACs (VOP3P)
#define PKFMA(acc, w, h) \
    asm("v_pk_fma_f32 %0, %1, %2, %0" : "+v"(acc) : "v"(w), "v"(h))
// split a float4 (4 consecutive VGPRs) into two f2 register pairs, no movs
#define SPLIT(v4, lo_, hi_) \
    { f2x2 u_ = __builtin_bit_cast(f2x2, (v4)); lo_ = u_.lo; hi_ = u_.hi; }

// + lane^1 via quad_perm DPP (VALU pipe, not LDS)
__device__ __forceinline__ float dppadd1(float v) {
    int s_ = __builtin_bit_cast(int, v);
    int p_ = __builtin_amdgcn_update_dpp(0, s_, 0xB1, 0xF, 0xF, true);
    return v + __builtin_bit_cast(float, p_);
}

// R19 = R15 (6 waves, 96 weight-floats/lane — the proven optimum) with the
// hard barrier replaced by a DATAFLOW PIPELINE: upstream-only waits on
// per-wave step counters + depth-4 ring buffers.
//
// Dependency graph (s0: Whh0/h1, s1: Wih1/xg, s2: Whh1/h2):
//   s0@i needs {w0,w2}>=i-1 (h1(i-1)) and {w4,w5}>=i-3 (h1 slot overwrite)
//   s1@i needs {w0,w2}>=i-1 (h1(i-1)) and {w1,w3}>=i-3 (xg slot overwrite)
//   s2@i needs {w4,w5}>=i-1 (xg(i-2)) and {w1,w3}>=i-1 (h2(i-3) peers)
// No wave ever waits on the slowest-of-6 (R15's barrier convoy, ~700cyc/iter;
// R17's min-of-6 slack-1 spin had the same convoy semantics and regressed).
// The pacer is the true L1 recurrence chain w0<->w2. Deadlock-free: counters
// are monotone, published unconditionally every step, and the sequential
// schedule satisfies every wait (marked-graph liveness).
//
// Wave->stage map (wave i -> SIMD i%4):
//   w0(s0,h0) w1(s2,h0) w2(s0,h1) w3(s2,h1,+flush) w4(s1,h0) w5(s1,h1)
// 4x-unrolled loop (ring indices literal); loop runs to 2052 so the chunk-31
// fc flush happens naturally at i=2050 (i%4==2 flush slot).
__global__ __launch_bounds__(384)
__attribute__((amdgpu_waves_per_eu(1, 2)))
void gru_fused(const float* __restrict__ x,
               const float* __restrict__ Wih0, const float* __restrict__ Whh0,
               const float* __restrict__ bih0, const float* __restrict__ bhh0,
               const float* __restrict__ Wih1, const float* __restrict__ Whh1,
               const float* __restrict__ bih1, const float* __restrict__ bhh1,
               const float* __restrict__ fcw, const float* __restrict__ fcb,
               float* __restrict__ out)
{
    const int t  = threadIdx.x;
    const int w  = t >> 6;          // wave 0..5
    const int j  = t & 63;          // lane
    const int s  = (w < 4) ? ((w & 1) ? 2 : 0) : 1;   // stage
    const int sw = (w < 4) ? (w >> 1) : (w & 1);      // dim half
    const int g  = j >> 1;          // local dim 0..31
    const int q  = j & 1;           // K-half
    const int d  = sw * 32 + g;     // dim 0..63
    const int b  = blockIdx.x;

    __shared__ __align__(16) float xs[TT * 2];       // 16 KB input
    __shared__ __align__(16) float h1b[4][HH];       // depth-4 ring
    __shared__ __align__(16) float h2b[4][HH];       // depth-4 ring
    __shared__ __align__(16) float4 xgb4[4][HH];     // depth-4 ring, packed
    __shared__ __align__(16) float fwS[HH];
    __shared__ int cnt[8];                           // per-wave step counters
    __shared__ float ring[256][65];                  // h2 history (pads LDS >80KB
                                                     // on purpose: 1-block/CU target)

// upstream-only wait: lane j<6 watches cnt[j] against i - lagv (per-lane lag)
#define WAITUP(i_)                                                             \
    {                                                                          \
        const int need_ = (i_) - lagv;                                         \
        while (true) {                                                         \
            int c_ = (j < 6) ? __hip_atomic_load(&cnt[j], __ATOMIC_ACQUIRE,    \
                                   __HIP_MEMORY_SCOPE_WORKGROUP)               \
                             : 0x7fffffff;                                     \
            if (__all(c_ >= need_)) break;                                     \
        }                                                                      \
    }
// release-publish own counter (drains ds_writes first)
#define PUBLISH(val_)                                                          \
    if (j == 0) __hip_atomic_store(&cnt[w], (val_), __ATOMIC_RELEASE,          \
                                   __HIP_MEMORY_SCOPE_WORKGROUP);

    // per-lane lag vector (lane j = watched wave j; BIG = don't care)
    int lagv = 1 << 20;
    if (s == 0) {            // w0,w2
        if (j == 0 || j == 2) lagv = 1;
        else if (j == 4 || j == 5) lagv = 3;
    } else if (s == 1) {     // w4,w5
        if (j == 0 || j == 2) lagv = 1;
        else if (j == 1 || j == 3) lagv = 3;
    } else {                 // w1,w3
        if (j == 1 || j == 3 || j == 4 || j == 5) lagv = 1;
    }

    // ---- 96 weight floats as 48 named f2 (3 rows x 32 cols) ----
    const float* Wm = (s == 0) ? Whh0 : (s == 1) ? Wih1 : Whh1;
    const float4* P0 = (const float4*)(Wm + (size_t)(0 * HH + d) * HH + q * 32);
    const float4* P1 = (const float4*)(Wm + (size_t)(1 * HH + d) * HH + q * 32);
    const float4* P2 = (const float4*)(Wm + (size_t)(2 * HH + d) * HH + q * 32);
    f2 wa0, wa1, wa2, wa3, wa4, wa5, wa6, wa7,
       wa8, wa9, wa10, wa11, wa12, wa13, wa14, wa15;
    f2 wb0, wb1, wb2, wb3, wb4, wb5, wb6, wb7,
       wb8, wb9, wb10, wb11, wb12, wb13, wb14, wb15;
    f2 wc0, wc1, wc2, wc3, wc4, wc5, wc6, wc7,
       wc8, wc9, wc10, wc11, wc12, wc13, wc14, wc15;
    {
        float4 v;
        v = P0[0]; SPLIT(v, wa0,  wa1);  v = P0[1]; SPLIT(v, wa2,  wa3);
        v = P0[2]; SPLIT(v, wa4,  wa5);  v = P0[3]; SPLIT(v, wa6,  wa7);
        v = P0[4]; SPLIT(v, wa8,  wa9);  v = P0[5]; SPLIT(v, wa10, wa11);
        v = P0[6]; SPLIT(v, wa12, wa13); v = P0[7]; SPLIT(v, wa14, wa15);
        v = P1[0]; SPLIT(v, wb0,  wb1);  v = P1[1]; SPLIT(v, wb2,  wb3);
        v = P1[2]; SPLIT(v, wb4,  wb5);  v = P1[3]; SPLIT(v, wb6,  wb7);
        v = P1[4]; SPLIT(v, wb8,  wb9);  v = P1[5]; SPLIT(v, wb10, wb11);
        v = P1[6]; SPLIT(v, wb12, wb13); v = P1[7]; SPLIT(v, wb14, wb15);
        v = P2[0]; SPLIT(v, wc0,  wc1);  v = P2[1]; SPLIT(v, wc2,  wc3);
        v = P2[2]; SPLIT(v, wc4,  wc5);  v = P2[3]; SPLIT(v, wc6,  wc7);
        v = P2[4]; SPLIT(v, wc8,  wc9);  v = P2[5]; SPLIT(v, wc10, wc11);
        v = P2[6]; SPLIT(v, wc12, wc13); v = P2[7]; SPLIT(v, wc14, wc15);
    }
    PIN2(wa0);  PIN2(wa1);  PIN2(wa2);  PIN2(wa3);
    PIN2(wa4);  PIN2(wa5);  PIN2(wa6);  PIN2(wa7);
    PIN2(wa8);  PIN2(wa9);  PIN2(wa10); PIN2(wa11);
    PIN2(wa12); PIN2(wa13); PIN2(wa14); PIN2(wa15);
    PIN2(wb0);  PIN2(wb1);  PIN2(wb2);  PIN2(wb3);
    PIN2(wb4);  PIN2(wb5);  PIN2(wb6);  PIN2(wb7);
    PIN2(wb8);  PIN2(wb9);  PIN2(wb10); PIN2(wb11);
    PIN2(wb12); PIN2(wb13); PIN2(wb14); PIN2(wb15);
    PIN2(wc0);  PIN2(wc1);  PIN2(wc2);  PIN2(wc3);
    PIN2(wc4);  PIN2(wc5);  PIN2(wc6);  PIN2(wc7);
    PIN2(wc8);  PIN2(wc9);  PIN2(wc10); PIN2(wc11);
    PIN2(wc12); PIN2(wc13); PIN2(wc14); PIN2(wc15);

    // biases (added AFTER the reduce, so loaded once per lane)
    float kb0, kb1, kb2, bi2 = 0.f;
    if (s == 0) {            // r,z: fold bih0+bhh0; n: bhh0 inside r*(), bih0 outside
        kb0 = bhh0[d] + bih0[d];
        kb1 = bhh0[HH + d] + bih0[HH + d];
        kb2 = bhh0[2 * HH + d];
        bi2 = bih0[2 * HH + d];
    } else if (s == 1) {
        kb0 = bih1[d]; kb1 = bih1[HH + d]; kb2 = bih1[2 * HH + d];
    } else {
        kb0 = bhh1[d]; kb1 = bhh1[HH + d]; kb2 = bhh1[2 * HH + d];
    }
    float wi0 = 0, wi1 = 0, wi2 = 0, wi3 = 0, wi4 = 0, wi5 = 0;
    if (s == 0) {
        wi0 = Wih0[d * 2];            wi1 = Wih0[d * 2 + 1];
        wi2 = Wih0[(HH + d) * 2];     wi3 = Wih0[(HH + d) * 2 + 1];
        wi4 = Wih0[(2 * HH + d) * 2]; wi5 = Wih0[(2 * HH + d) * 2 + 1];
    }
    const float fcbv = fcb[0];

    // ---- preload x, zero state, init counters ----
    {
        const float4* xp  = (const float4*)(x + (size_t)b * TT * 2);
        float4*       xsp = (float4*)xs;
        for (int i2 = t; i2 < TT * 2 / 4; i2 += 384) xsp[i2] = xp[i2];
    }
    if (t < 4 * HH) { ((float*)h1b)[t] = 0.f; ((float*)h2b)[t] = 0.f; }
    if (t < HH) fwS[t] = fcw[t];
    if (t < 8) cnt[t] = -1;
    __syncthreads();    // preload + counter init visible

    float hreg = 0.f;   // s0: h1[d]; s2: h2[d] (tracked redundantly by 2 lanes)

// One timestep. PC=i&3, PP=(i-1)&3, PX=(i-2)&3 literals; FL on i%4==2 steps.
#define STEP(IDX, PC, PP, PX, FL)                                              \
    {                                                                          \
        const int i_ = (IDX);                                                  \
        WAITUP(i_);                                                            \
        const bool act = (s == 0) ? (i_ < TT)                                  \
                       : (s == 1) ? (i_ >= 1 && i_ <= TT)                      \
                                  : (i_ >= 2 && i_ <= TT + 1);                 \
        if (act) {                                                             \
            const float4* hp = ((const float4*)((s < 2) ? h1b[PP] : h2b[PP])) + q * 8; \
            f2 h0, h1, h2, h3, h4, h5, h6, h7,                                 \
               h8, h9, h10, h11, h12, h13, h14, h15;                           \
            {                                                                  \
                float4 v_;                                                     \
                v_ = hp[0]; SPLIT(v_, h0,  h1);  v_ = hp[1]; SPLIT(v_, h2,  h3); \
                v_ = hp[2]; SPLIT(v_, h4,  h5);  v_ = hp[3]; SPLIT(v_, h6,  h7); \
                v_ = hp[4]; SPLIT(v_, h8,  h9);  v_ = hp[5]; SPLIT(v_, h10, h11);\
                v_ = hp[6]; SPLIT(v_, h12, h13); v_ = hp[7]; SPLIT(v_, h14, h15);\
            }                                                                  \
            f2 aR = {0.f, 0.f}, aZ = {0.f, 0.f}, aN = {0.f, 0.f};              \
            PKFMA(aR, wa0,  h0);  PKFMA(aZ, wb0,  h0);  PKFMA(aN, wc0,  h0);   \
            PKFMA(aR, wa1,  h1);  PKFMA(aZ, wb1,  h1);  PKFMA(aN, wc1,  h1);   \
            PKFMA(aR, wa2,  h2);  PKFMA(aZ, wb2,  h2);  PKFMA(aN, wc2,  h2);   \
            PKFMA(aR, wa3,  h3);  PKFMA(aZ, wb3,  h3);  PKFMA(aN, wc3,  h3);   \
            PKFMA(aR, wa4,  h4);  PKFMA(aZ, wb4,  h4);  PKFMA(aN, wc4,  h4);   \
            PKFMA(aR, wa5,  h5);  PKFMA(aZ, wb5,  h5);  PKFMA(aN, wc5,  h5);   \
            PKFMA(aR, wa6,  h6);  PKFMA(aZ, wb6,  h6);  PKFMA(aN, wc6,  h6);   \
            PKFMA(aR, wa7,  h7);  PKFMA(aZ, wb7,  h7);  PKFMA(aN, wc7,  h7);   \
            PKFMA(aR, wa8,  h8);  PKFMA(aZ, wb8,  h8);  PKFMA(aN, wc8,  h8);   \
            PKFMA(aR, wa9,  h9);  PKFMA(aZ, wb9,  h9);  PKFMA(aN, wc9,  h9);   \
            PKFMA(aR, wa10, h10); PKFMA(aZ, wb10, h10); PKFMA(aN, wc10, h10);  \
            PKFMA(aR, wa11, h11); PKFMA(aZ, wb11, h11); PKFMA(aN, wc11, h11);  \
            PKFMA(aR, wa12, h12); PKFMA(aZ, wb12, h12); PKFMA(aN, wc12, h12);  \
            PKFMA(aR, wa13, h13); PKFMA(aZ, wb13, h13); PKFMA(aN, wc13, h13);  \
            PKFMA(aR, wa14, h14); PKFMA(aZ, wb14, h14); PKFMA(aN, wc14, h14);  \
            PKFMA(aR, wa15, h15); PKFMA(aZ, wb15, h15); PKFMA(aN, wc15, h15);  \
            float sr = aR.x + aR.y, sz = aZ.x + aZ.y, sn = aN.x + aN.y;        \
            sr = dppadd1(sr); sz = dppadd1(sz); sn = dppadd1(sn);              \
            sr += kb0; sz += kb1; sn += kb2;                                   \
            if (s == 0) {                                                      \
                f2 xv = *(const f2*)(xs + 2 * i_);                             \
                float rr = sigm (fmaf(wi0, xv.x, fmaf(wi1, xv.y, sr)));        \
                float zz = sigm (fmaf(wi2, xv.x, fmaf(wi3, xv.y, sz)));        \
                float nn = ftanh(fmaf(wi4, xv.x, fmaf(wi5, xv.y, bi2)) + rr * sn); \
                hreg = (1.f - zz) * nn + zz * hreg;                            \
                if (q == 0) h1b[PC][d] = hreg;                                 \
            } else if (s == 1) {                                               \
                if (q == 0) xgb4[PP][d] = make_float4(sr, sz, sn, 0.f);        \
            } else {                                                           \
                float4 xg = xgb4[PX][d];                                       \
                float rr = sigm (xg.x + sr);                                   \
                float zz = sigm (xg.y + sz);                                   \
                float nn = ftanh(xg.z + rr * sn);                              \
                hreg = (1.f - zz) * nn + zz * hreg;                            \
                if (q == 0) {                                                  \
                    h2b[PC][d] = hreg;                                         \
                    ring[(i_ - 2) & 255][d] = hreg;                            \
                }                                                              \
            }                                                                  \
        }                                                                      \
        if (FL && w == 3 && i_ >= 66 && ((i_ - 66) & 63) == 0) {               \
            const int tt = ((i_ - 66) >> 6) * 64 + j;                          \
            const float* rr2 = ring[tt & 255];                                 \
            float acc0 = 0.f, acc1 = 0.f;                                      \
            _Pragma("unroll")                                                  \
            for (int k = 0; k < 64; k += 2) {                                  \
                acc0 += rr2[k]     * fwS[k];                                   \
                acc1 += rr2[k + 1] * fwS[k + 1];                               \
            }                                                                  \
            out[(size_t)b * TT + tt] = acc0 + acc1 + fcbv;                     \
        }                                                                      \
        PUBLISH(i_);                                                           \
    }

    // loop to 2052: chunk-31 flush happens at i=2050 (flush slot i%4==2);
    // steps > TT+1 are act-false but still publish (liveness).
    for (int ii = 0; ii < TT + 4; ii += 4) {
        STEP(ii,     0, 3, 2, false);
        STEP(ii + 1, 1, 0, 3, false);
        STEP(ii + 2, 2, 1, 0, true);
        STEP(ii + 3, 3, 2, 1, false);
    }
#undef STEP
}

extern "C" void kernel_launch(void* const* d_in, const int* in_sizes, int n_in,
                              void* d_out, int out_size, void* d_ws, size_t ws_size,
                              hipStream_t stream) {
    const float* x    = (const float*)d_in[0];
    const float* Wih0 = (const float*)d_in[1];
    const float* Whh0 = (const float*)d_in[2];
    const float* bih0 = (const float*)d_in[3];
    const float* bhh0 = (const float*)d_in[4];
    const float* Wih1 = (const float*)d_in[5];
    const float* Whh1 = (const float*)d_in[6];
    const float* bih1 = (const float*)d_in[7];
    const float* bhh1 = (const float*)d_in[8];
    const float* fcw  = (const float*)d_in[9];
    const float* fcb  = (const float*)d_in[10];
    float* out = (float*)d_out;

    gru_fused<<<BB, 384, 0, stream>>>(x, Wih0, Whh0, bih0, bhh0,
                                      Wih1, Whh1, bih1, bhh1, fcw, fcb, out);
}

// Round 21
// 1010.980 us; speedup vs baseline: 1.6202x; 1.1340x over previous
//
#include <hip/hip_runtime.h>

#define BB 128
#define TT 2048
#define HH 64

typedef float2 f2;
typedef _Float16 half_t;
typedef half_t hf2 __attribute__((ext_vector_type(2)));
struct f2x2 { f2 lo, hi; };

__device__ __forceinline__ float sigm(float v) {
    return __builtin_amdgcn_rcpf(1.0f + __expf(-v));
}
__device__ __forceinline__ float ftanh(float v) {
    float e = __expf(-2.0f * fabsf(v));
    float r = (1.0f - e) * __builtin_amdgcn_rcpf(1.0f + e);
    return copysignf(r, v);
}

#define PIN2(v) asm volatile("" : "+v"(v))
// packed fp32 FMA: 1 inst / 2 MACs (VOP3P)
#define PKFMA(acc, w, h) \
    asm("v_pk_fma_f32 %0, %1, %2, %0" : "+v"(acc) : "v"(w), "v"(h))
// f16 dot2: acc += lo(w)*lo(h) + hi(w)*hi(h); operands are float-typed regs
// CARRYING f16-pair bit patterns (type is just bits to the instruction).
#define FDOT2(acc, ws, hs) \
    asm("v_dot2_f32_f16 %0, %1, %2, %0" : "+v"(acc) : "v"(ws), "v"(hs))
// pack two f32 into one float slot holding 2 f16 (RTNE via cast)
#define PKH(dst, a, b) \
    { hf2 t_ = {(half_t)(a), (half_t)(b)}; dst = __builtin_bit_cast(float, t_); }
#define SPLIT(v4, lo_, hi_) \
    { f2x2 u_ = __builtin_bit_cast(f2x2, (v4)); lo_ = u_.lo; hi_ = u_.hi; }

// + lane^1 via quad_perm DPP (VALU pipe, not LDS)
__device__ __forceinline__ float dppadd1(float v) {
    int s_ = __builtin_bit_cast(int, v);
    int p_ = __builtin_amdgcn_update_dpp(0, s_, 0xB1, 0xF, 0xF, true);
    return v + __builtin_bit_cast(float, p_);
}

// R21 = R20 with the token-pasting bug fixed (ROW16 takes ZA..ZD explicitly;
// `Z##1.z` died because `1.z` lexes as one pp-number token).
//
// FOUR waves (1 per SIMD — R15's 6-wave had 2 SIMDs carrying double issue;
// R17/R19 proved spin-sync loses to s_barrier, so the lever is fewer waves
// at the same barrier). f16 packing makes it fit:
//   w0/w1 (role A, dim halves): L1 exactly as R15-s0 — Whh0 fp32 (96 regs,
//     pk_fma, fp32 h1 recurrence = numerically clean) + publishes h1 as
//     fp32 AND f16.
//   w2/w3 (role B): L2 — Wih1 AND Whh1 as f16 pairs packed into the SAME
//     48 named f2 slots (96 VGPRs), v_dot2_f32_f16 with fp32 accumulate.
//     xg lives in REGISTERS across iterations (never in LDS): B@i computes
//     xg(i-1)=Wih1*h16(i-1) and gates h2(i-2) with xg(i-2) from last iter.
// Skew (1 s_barrier/step): A@i: h1(i) from h1(i-1); B@i: xg(i-1) from
// h16(i-1) [A wrote @ i-1], h2(i-2) from xg(i-2) [B regs] + h2_16(i-3).
// fc head: w3 flushes 64 outs every 64 steps from the fp32 ring.
// f16 exposure: h1->xg (feed-forward) and L2 dot inputs only; L1 pure fp32.
__global__ __launch_bounds__(256)
__attribute__((amdgpu_waves_per_eu(1, 1)))
void gru_fused(const float* __restrict__ x,
               const float* __restrict__ Wih0, const float* __restrict__ Whh0,
               const float* __restrict__ bih0, const float* __restrict__ bhh0,
               const float* __restrict__ Wih1, const float* __restrict__ Whh1,
               const float* __restrict__ bih1, const float* __restrict__ bhh1,
               const float* __restrict__ fcw, const float* __restrict__ fcb,
               float* __restrict__ out)
{
    const int t  = threadIdx.x;
    const int w  = t >> 6;          // wave 0..3
    const int j  = t & 63;          // lane
    const int sw = w & 1;           // dim half
    const int g  = j >> 1;          // local dim 0..31
    const int q  = j & 1;           // K-half
    const int d  = sw * 32 + g;     // dim 0..63
    const int b  = blockIdx.x;
    const bool isA = (w < 2);

    __shared__ __align__(16) float xs[TT * 2];        // 16 KB input
    __shared__ __align__(16) float  h1b[2][HH];       // fp32 h1, parity
    __shared__ __align__(16) half_t h16[2][HH];       // f16 h1, parity
    __shared__ __align__(16) half_t h2b16[2][HH];     // f16 h2, parity
    __shared__ __align__(16) float fwS[HH];
    __shared__ float ring[256][65];                   // h2 history fp32 (pads
                                                      // LDS >80KB: 1-blk/CU target)

    // ---- 48 f2 weight names (96 VGPRs), role-unioned ----
    f2 wa0, wa1, wa2, wa3, wa4, wa5, wa6, wa7,
       wa8, wa9, wa10, wa11, wa12, wa13, wa14, wa15;
    f2 wb0, wb1, wb2, wb3, wb4, wb5, wb6, wb7,
       wb8, wb9, wb10, wb11, wb12, wb13, wb14, wb15;
    f2 wc0, wc1, wc2, wc3, wc4, wc5, wc6, wc7,
       wc8, wc9, wc10, wc11, wc12, wc13, wc14, wc15;

    if (isA) {
        // A: Whh0 rows {d,64+d,128+d} x cols [32q,32q+32) as fp32 f2 pairs
        const float4* P0 = (const float4*)(Whh0 + (size_t)(0 * HH + d) * HH + q * 32);
        const float4* P1 = (const float4*)(Whh0 + (size_t)(1 * HH + d) * HH + q * 32);
        const float4* P2 = (const float4*)(Whh0 + (size_t)(2 * HH + d) * HH + q * 32);
        float4 v;
        v = P0[0]; SPLIT(v, wa0,  wa1);  v = P0[1]; SPLIT(v, wa2,  wa3);
        v = P0[2]; SPLIT(v, wa4,  wa5);  v = P0[3]; SPLIT(v, wa6,  wa7);
        v = P0[4]; SPLIT(v, wa8,  wa9);  v = P0[5]; SPLIT(v, wa10, wa11);
        v = P0[6]; SPLIT(v, wa12, wa13); v = P0[7]; SPLIT(v, wa14, wa15);
        v = P1[0]; SPLIT(v, wb0,  wb1);  v = P1[1]; SPLIT(v, wb2,  wb3);
        v = P1[2]; SPLIT(v, wb4,  wb5);  v = P1[3]; SPLIT(v, wb6,  wb7);
        v = P1[4]; SPLIT(v, wb8,  wb9);  v = P1[5]; SPLIT(v, wb10, wb11);
        v = P1[6]; SPLIT(v, wb12, wb13); v = P1[7]; SPLIT(v, wb14, wb15);
        v = P2[0]; SPLIT(v, wc0,  wc1);  v = P2[1]; SPLIT(v, wc2,  wc3);
        v = P2[2]; SPLIT(v, wc4,  wc5);  v = P2[3]; SPLIT(v, wc6,  wc7);
        v = P2[4]; SPLIT(v, wc8,  wc9);  v = P2[5]; SPLIT(v, wc10, wc11);
        v = P2[6]; SPLIT(v, wc12, wc13); v = P2[7]; SPLIT(v, wc14, wc15);
    } else {
        // B: Wih1 rows (x-side) then Whh1 rows (h-side), f16 pairs packed
        // into float slots. Mapping:
        //   x-r: wa0-7   x-z: wa8-15   x-n: wb0-7
        //   h-r: wb8-15  h-z: wc0-7    h-n: wc8-15
        const float4* X0 = (const float4*)(Wih1 + (size_t)(0 * HH + d) * HH + q * 32);
        const float4* X1 = (const float4*)(Wih1 + (size_t)(1 * HH + d) * HH + q * 32);
        const float4* X2 = (const float4*)(Wih1 + (size_t)(2 * HH + d) * HH + q * 32);
        const float4* H0 = (const float4*)(Whh1 + (size_t)(0 * HH + d) * HH + q * 32);
        const float4* H1 = (const float4*)(Whh1 + (size_t)(1 * HH + d) * HH + q * 32);
        const float4* H2 = (const float4*)(Whh1 + (size_t)(2 * HH + d) * HH + q * 32);
        float4 v;
        v = X0[0]; PKH(wa0.x, v.x, v.y); PKH(wa0.y, v.z, v.w);
        v = X0[1]; PKH(wa1.x, v.x, v.y); PKH(wa1.y, v.z, v.w);
        v = X0[2]; PKH(wa2.x, v.x, v.y); PKH(wa2.y, v.z, v.w);
        v = X0[3]; PKH(wa3.x, v.x, v.y); PKH(wa3.y, v.z, v.w);
        v = X0[4]; PKH(wa4.x, v.x, v.y); PKH(wa4.y, v.z, v.w);
        v = X0[5]; PKH(wa5.x, v.x, v.y); PKH(wa5.y, v.z, v.w);
        v = X0[6]; PKH(wa6.x, v.x, v.y); PKH(wa6.y, v.z, v.w);
        v = X0[7]; PKH(wa7.x, v.x, v.y); PKH(wa7.y, v.z, v.w);
        v = X1[0]; PKH(wa8.x, v.x, v.y); PKH(wa8.y, v.z, v.w);
        v = X1[1]; PKH(wa9.x, v.x, v.y); PKH(wa9.y, v.z, v.w);
        v = X1[2]; PKH(wa10.x, v.x, v.y); PKH(wa10.y, v.z, v.w);
        v = X1[3]; PKH(wa11.x, v.x, v.y); PKH(wa11.y, v.z, v.w);
        v = X1[4]; PKH(wa12.x, v.x, v.y); PKH(wa12.y, v.z, v.w);
        v = X1[5]; PKH(wa13.x, v.x, v.y); PKH(wa13.y, v.z, v.w);
        v = X1[6]; PKH(wa14.x, v.x, v.y); PKH(wa14.y, v.z, v.w);
        v = X1[7]; PKH(wa15.x, v.x, v.y); PKH(wa15.y, v.z, v.w);
        v = X2[0]; PKH(wb0.x, v.x, v.y); PKH(wb0.y, v.z, v.w);
        v = X2[1]; PKH(wb1.x, v.x, v.y); PKH(wb1.y, v.z, v.w);
        v = X2[2]; PKH(wb2.x, v.x, v.y); PKH(wb2.y, v.z, v.w);
        v = X2[3]; PKH(wb3.x, v.x, v.y); PKH(wb3.y, v.z, v.w);
        v = X2[4]; PKH(wb4.x, v.x, v.y); PKH(wb4.y, v.z, v.w);
        v = X2[5]; PKH(wb5.x, v.x, v.y); PKH(wb5.y, v.z, v.w);
        v = X2[6]; PKH(wb6.x, v.x, v.y); PKH(wb6.y, v.z, v.w);
        v = X2[7]; PKH(wb7.x, v.x, v.y); PKH(wb7.y, v.z, v.w);
        v = H0[0]; PKH(wb8.x, v.x, v.y); PKH(wb8.y, v.z, v.w);
        v = H0[1]; PKH(wb9.x, v.x, v.y); PKH(wb9.y, v.z, v.w);
        v = H0[2]; PKH(wb10.x, v.x, v.y); PKH(wb10.y, v.z, v.w);
        v = H0[3]; PKH(wb11.x, v.x, v.y); PKH(wb11.y, v.z, v.w);
        v = H0[4]; PKH(wb12.x, v.x, v.y); PKH(wb12.y, v.z, v.w);
        v = H0[5]; PKH(wb13.x, v.x, v.y); PKH(wb13.y, v.z, v.w);
        v = H0[6]; PKH(wb14.x, v.x, v.y); PKH(wb14.y, v.z, v.w);
        v = H0[7]; PKH(wb15.x, v.x, v.y); PKH(wb15.y, v.z, v.w);
        v = H1[0]; PKH(wc0.x, v.x, v.y); PKH(wc0.y, v.z, v.w);
        v = H1[1]; PKH(wc1.x, v.x, v.y); PKH(wc1.y, v.z, v.w);
        v = H1[2]; PKH(wc2.x, v.x, v.y); PKH(wc2.y, v.z, v.w);
        v = H1[3]; PKH(wc3.x, v.x, v.y); PKH(wc3.y, v.z, v.w);
        v = H1[4]; PKH(wc4.x, v.x, v.y); PKH(wc4.y, v.z, v.w);
        v = H1[5]; PKH(wc5.x, v.x, v.y); PKH(wc5.y, v.z, v.w);
        v = H1[6]; PKH(wc6.x, v.x, v.y); PKH(wc6.y, v.z, v.w);
        v = H1[7]; PKH(wc7.x, v.x, v.y); PKH(wc7.y, v.z, v.w);
        v = H2[0]; PKH(wc8.x, v.x, v.y); PKH(wc8.y, v.z, v.w);
        v = H2[1]; PKH(wc9.x, v.x, v.y); PKH(wc9.y, v.z, v.w);
        v = H2[2]; PKH(wc10.x, v.x, v.y); PKH(wc10.y, v.z, v.w);
        v = H2[3]; PKH(wc11.x, v.x, v.y); PKH(wc11.y, v.z, v.w);
        v = H2[4]; PKH(wc12.x, v.x, v.y); PKH(wc12.y, v.z, v.w);
        v = H2[5]; PKH(wc13.x, v.x, v.y); PKH(wc13.y, v.z, v.w);
        v = H2[6]; PKH(wc14.x, v.x, v.y); PKH(wc14.y, v.z, v.w);
        v = H2[7]; PKH(wc15.x, v.x, v.y); PKH(wc15.y, v.z, v.w);
    }
    PIN2(wa0);  PIN2(wa1);  PIN2(wa2);  PIN2(wa3);
    PIN2(wa4);  PIN2(wa5);  PIN2(wa6);  PIN2(wa7);
    PIN2(wa8);  PIN2(wa9);  PIN2(wa10); PIN2(wa11);
    PIN2(wa12); PIN2(wa13); PIN2(wa14); PIN2(wa15);
    PIN2(wb0);  PIN2(wb1);  PIN2(wb2);  PIN2(wb3);
    PIN2(wb4);  PIN2(wb5);  PIN2(wb6);  PIN2(wb7);
    PIN2(wb8);  PIN2(wb9);  PIN2(wb10); PIN2(wb11);
    PIN2(wb12); PIN2(wb13); PIN2(wb14); PIN2(wb15);
    PIN2(wc0);  PIN2(wc1);  PIN2(wc2);  PIN2(wc3);
    PIN2(wc4);  PIN2(wc5);  PIN2(wc6);  PIN2(wc7);
    PIN2(wc8);  PIN2(wc9);  PIN2(wc10); PIN2(wc11);
    PIN2(wc12); PIN2(wc13); PIN2(wc14); PIN2(wc15);

    // ---- biases / input-side constants ----
    float kb0 = 0, kb1 = 0, kb2 = 0, bi2 = 0;       // A: L1 combine
    float kbx0 = 0, kbx1 = 0, kbx2 = 0;             // B: bih1
    float kbh0 = 0, kbh1 = 0, kbh2 = 0;             // B: bhh1
    float wi0 = 0, wi1 = 0, wi2 = 0, wi3 = 0, wi4 = 0, wi5 = 0;
    if (isA) {
        kb0 = bhh0[d] + bih0[d];
        kb1 = bhh0[HH + d] + bih0[HH + d];
        kb2 = bhh0[2 * HH + d];
        bi2 = bih0[2 * HH + d];
        wi0 = Wih0[d * 2];            wi1 = Wih0[d * 2 + 1];
        wi2 = Wih0[(HH + d) * 2];     wi3 = Wih0[(HH + d) * 2 + 1];
        wi4 = Wih0[(2 * HH + d) * 2]; wi5 = Wih0[(2 * HH + d) * 2 + 1];
    } else {
        kbx0 = bih1[d]; kbx1 = bih1[HH + d]; kbx2 = bih1[2 * HH + d];
        kbh0 = bhh1[d]; kbh1 = bhh1[HH + d]; kbh2 = bhh1[2 * HH + d];
    }
    const float fcbv = fcb[0];

    // ---- preload x, zero state ----
    {
        const float4* xp  = (const float4*)(x + (size_t)b * TT * 2);
        float4*       xsp = (float4*)xs;
        for (int i2 = t; i2 < TT * 2 / 4; i2 += 256) xsp[i2] = xp[i2];
    }
    if (t < 2 * HH) {
        ((float*)h1b)[t] = 0.f;
        ((half_t*)h16)[t]   = (half_t)0.f;
        ((half_t*)h2b16)[t] = (half_t)0.f;
    }
    if (t < HH) fwS[t] = fcw[t];

    float hreg = 0.f;                    // A: h1[d];  B: h2[d]
    float xro = 0.f, xzo = 0.f, xno = 0.f;  // B: xg(i-2) carried in registers

// 16 dot2 of one row: weight slots S0..S7 (f2, 2 halfs per component)
// against four float4 h-vectors ZA..ZD (explicit names — no token pasting).
#define ROW16(acc, S0,S1,S2,S3,S4,S5,S6,S7, ZA,ZB,ZC,ZD)                       \
    FDOT2(acc, S0.x, ZA.x); FDOT2(acc, S0.y, ZA.y);                            \
    FDOT2(acc, S1.x, ZA.z); FDOT2(acc, S1.y, ZA.w);                            \
    FDOT2(acc, S2.x, ZB.x); FDOT2(acc, S2.y, ZB.y);                            \
    FDOT2(acc, S3.x, ZB.z); FDOT2(acc, S3.y, ZB.w);                            \
    FDOT2(acc, S4.x, ZC.x); FDOT2(acc, S4.y, ZC.y);                            \
    FDOT2(acc, S5.x, ZC.z); FDOT2(acc, S5.y, ZC.w);                            \
    FDOT2(acc, S6.x, ZD.x); FDOT2(acc, S6.y, ZD.y);                            \
    FDOT2(acc, S7.x, ZD.z); FDOT2(acc, S7.y, ZD.w);

#define STEP(IDX, PC, PP, FL)                                                  \
    {                                                                          \
        __syncthreads();                                                       \
        const int i_ = (IDX);                                                  \
        if (isA) {                                                             \
            if (i_ < TT) {                                                     \
                const float4* hp = ((const float4*)h1b[PP]) + q * 8;           \
                f2 h0, h1, h2, h3, h4, h5, h6, h7,                             \
                   h8, h9, h10, h11, h12, h13, h14, h15;                       \
                {                                                              \
                    float4 v_;                                                 \
                    v_ = hp[0]; SPLIT(v_, h0,  h1);  v_ = hp[1]; SPLIT(v_, h2,  h3); \
                    v_ = hp[2]; SPLIT(v_, h4,  h5);  v_ = hp[3]; SPLIT(v_, h6,  h7); \
                    v_ = hp[4]; SPLIT(v_, h8,  h9);  v_ = hp[5]; SPLIT(v_, h10, h11);\
                    v_ = hp[6]; SPLIT(v_, h12, h13); v_ = hp[7]; SPLIT(v_, h14, h15);\
                }                                                              \
                f2 aR = {0.f, 0.f}, aZ = {0.f, 0.f}, aN = {0.f, 0.f};          \
                PKFMA(aR, wa0,  h0);  PKFMA(aZ, wb0,  h0);  PKFMA(aN, wc0,  h0);   \
                PKFMA(aR, wa1,  h1);  PKFMA(aZ, wb1,  h1);  PKFMA(aN, wc1,  h1);   \
                PKFMA(aR, wa2,  h2);  PKFMA(aZ, wb2,  h2);  PKFMA(aN, wc2,  h2);   \
                PKFMA(aR, wa3,  h3);  PKFMA(aZ, wb3,  h3);  PKFMA(aN, wc3,  h3);   \
                PKFMA(aR, wa4,  h4);  PKFMA(aZ, wb4,  h4);  PKFMA(aN, wc4,  h4);   \
                PKFMA(aR, wa5,  h5);  PKFMA(aZ, wb5,  h5);  PKFMA(aN, wc5,  h5);   \
                PKFMA(aR, wa6,  h6);  PKFMA(aZ, wb6,  h6);  PKFMA(aN, wc6,  h6);   \
                PKFMA(aR, wa7,  h7);  PKFMA(aZ, wb7,  h7);  PKFMA(aN, wc7,  h7);   \
                PKFMA(aR, wa8,  h8);  PKFMA(aZ, wb8,  h8);  PKFMA(aN, wc8,  h8);   \
                PKFMA(aR, wa9,  h9);  PKFMA(aZ, wb9,  h9);  PKFMA(aN, wc9,  h9);   \
                PKFMA(aR, wa10, h10); PKFMA(aZ, wb10, h10); PKFMA(aN, wc10, h10);  \
                PKFMA(aR, wa11, h11); PKFMA(aZ, wb11, h11); PKFMA(aN, wc11, h11);  \
                PKFMA(aR, wa12, h12); PKFMA(aZ, wb12, h12); PKFMA(aN, wc12, h12);  \
                PKFMA(aR, wa13, h13); PKFMA(aZ, wb13, h13); PKFMA(aN, wc13, h13);  \
                PKFMA(aR, wa14, h14); PKFMA(aZ, wb14, h14); PKFMA(aN, wc14, h14);  \
                PKFMA(aR, wa15, h15); PKFMA(aZ, wb15, h15); PKFMA(aN, wc15, h15);  \
                float sr = aR.x + aR.y, sz = aZ.x + aZ.y, sn = aN.x + aN.y;    \
                sr = dppadd1(sr); sz = dppadd1(sz); sn = dppadd1(sn);          \
                sr += kb0; sz += kb1; sn += kb2;                               \
                f2 xv = *(const f2*)(xs + 2 * i_);                             \
                float rr = sigm (fmaf(wi0, xv.x, fmaf(wi1, xv.y, sr)));        \
                float zz = sigm (fmaf(wi2, xv.x, fmaf(wi3, xv.y, sz)));        \
                float nn = ftanh(fmaf(wi4, xv.x, fmaf(wi5, xv.y, bi2)) + rr * sn); \
                hreg = (1.f - zz) * nn + zz * hreg;                            \
                if (q == 0) {                                                  \
                    h1b[PC][d] = hreg;                                         \
                    h16[PC][d] = (half_t)hreg;                                 \
                }                                                              \
            }                                                                  \
        } else {                                                               \
            float axr = 0.f, axz = 0.f, axn = 0.f;                             \
            const bool doX = (i_ >= 1 && i_ <= TT);                            \
            if (doX) {                   /* xg(i-1) = Wih1 * h16(i-1) */       \
                const float4* zp = ((const float4*)h16[PP]) + q * 4;           \
                float4 Z0 = zp[0], Z1 = zp[1], Z2 = zp[2], Z3 = zp[3];         \
                ROW16(axr, wa0, wa1, wa2,  wa3,  wa4,  wa5,  wa6,  wa7,  Z0, Z1, Z2, Z3); \
                ROW16(axz, wa8, wa9, wa10, wa11, wa12, wa13, wa14, wa15, Z0, Z1, Z2, Z3); \
                ROW16(axn, wb0, wb1, wb2,  wb3,  wb4,  wb5,  wb6,  wb7,  Z0, Z1, Z2, Z3); \
                axr = dppadd1(axr); axz = dppadd1(axz); axn = dppadd1(axn);    \
            }                                                                  \
            if (i_ >= 2) {               /* h2(i-2) from xg(i-2), h2(i-3) */   \
                const float4* yp = ((const float4*)h2b16[PP]) + q * 4;         \
                float4 Y0 = yp[0], Y1 = yp[1], Y2 = yp[2], Y3 = yp[3];         \
                float ahr = 0.f, ahz = 0.f, ahn = 0.f;                         \
                ROW16(ahr, wb8, wb9, wb10, wb11, wb12, wb13, wb14, wb15, Y0, Y1, Y2, Y3); \
                ROW16(ahz, wc0, wc1, wc2,  wc3,  wc4,  wc5,  wc6,  wc7,  Y0, Y1, Y2, Y3); \
                ROW16(ahn, wc8, wc9, wc10, wc11, wc12, wc13, wc14, wc15, Y0, Y1, Y2, Y3); \
                ahr = dppadd1(ahr) + kbh0;                                     \
                ahz = dppadd1(ahz) + kbh1;                                     \
                ahn = dppadd1(ahn) + kbh2;                                     \
                float rr = sigm (xro + ahr);                                   \
                float zz = sigm (xzo + ahz);                                   \
                float nn = ftanh(xno + rr * ahn);                              \
                hreg = (1.f - zz) * nn + zz * hreg;                            \
                if (q == 0) {                                                  \
                    h2b16[PC][d] = (half_t)hreg;                               \
                    ring[(i_ - 2) & 255][d] = hreg;                            \
                }                                                              \
            }                                                                  \
            if (doX) { xro = axr + kbx0; xzo = axz + kbx1; xno = axn + kbx2; } \
            if (FL && w == 3 && i_ >= 66 && ((i_ - 66) & 63) == 0) {           \
                const int tt = ((i_ - 66) >> 6) * 64 + j;                      \
                const float* rr2 = ring[tt & 255];                             \
                float acc0 = 0.f, acc1 = 0.f;                                  \
                _Pragma("unroll")                                              \
                for (int k = 0; k < 64; k += 2) {                              \
                    acc0 += rr2[k]     * fwS[k];                               \
                    acc1 += rr2[k + 1] * fwS[k + 1];                           \
                }                                                              \
                out[(size_t)b * TT + tt] = acc0 + acc1 + fcbv;                 \
            }                                                                  \
        }                                                                      \
    }

    for (int ii = 0; ii < TT + 2; ii += 2) {
        STEP(ii,     0, 1, true);     // even step: parity (0,1), flush check
        STEP(ii + 1, 1, 0, false);    // odd  step: parity (1,0)
    }
#undef STEP
#undef ROW16

    __syncthreads();
    if (w == 3) {                                // final chunk: t = 1984..2047
        const int tt = 31 * 64 + j;
        const float* rr2 = ring[tt & 255];
        float acc0 = 0.f, acc1 = 0.f;
        #pragma unroll
        for (int k = 0; k < 64; k += 2) {
            acc0 += rr2[k]     * fwS[k];
            acc1 += rr2[k + 1] * fwS[k + 1];
        }
        out[(size_t)b * TT + tt] = acc0 + acc1 + fcbv;
    }
}

extern "C" void kernel_launch(void* const* d_in, const int* in_sizes, int n_in,
                              void* d_out, int out_size, void* d_ws, size_t ws_size,
                              hipStream_t stream) {
    const float* x    = (const float*)d_in[0];
    const float* Wih0 = (const float*)d_in[1];
    const float* Whh0 = (const float*)d_in[2];
    const float* bih0 = (const float*)d_in[3];
    const float* bhh0 = (const float*)d_in[4];
    const float* Wih1 = (const float*)d_in[5];
    const float* Whh1 = (const float*)d_in[6];
    const float* bih1 = (const float*)d_in[7];
    const float* bhh1 = (const float*)d_in[8];
    const float* fcw  = (const float*)d_in[9];
    const float* fcb  = (const float*)d_in[10];
    float* out = (float*)d_out;

    gru_fused<<<BB, 256, 0, stream>>>(x, Wih0, Whh0, bih0, bhh0,
                                      Wih1, Whh1, bih1, bhh1, fcw, fcb, out);
}